// Round 3
// baseline (482.797 us; speedup 1.0000x reference)
//
#include <hip/hip_runtime.h>

#define CT  0.7f
#define CPT 0.5f
#define BB  32
#define TT  2048
#define DD  512
#define MAXR 1025            // T/2 + 1
#define QCAP (BB * MAXR)     // 32800
#define NBLK 512

// ws layout (zeroed by one hipMemsetAsync):
//   wsF[0]=attn-level acc, wsF[1]=feat-level acc,
//   wsI[2]=queue reserve count (== n_qual when done), wsI[3]=done-block ticket,
//   wsI[4]=rows_done (producers), wsI[5]=work-steal claim counter
//   q[QCAP] at byte 256: packed u64 {bit63=ready, rep<<28, cnt<<16, pos}
//   (inv_cnt / inv_rep recomputed by consumer from cnt/rep — keeps payload in ONE
//    atomic word so cross-XCD publish needs no separate data fence)

__global__ __launch_bounds__(256) void k_fused(const float* __restrict__ attn,
                                               const float* __restrict__ feat,
                                               unsigned long long* __restrict__ q,
                                               float* wsF, int* wsI,
                                               float* __restrict__ out) {
    const int t    = threadIdx.x;
    const int lane = t & 63;
    const int wv   = t >> 6;

    __shared__ float s_cnt[MAXR], s_sum[MAXR], s_rep[MAXR], s_mse[MAXR];
    __shared__ int   s_pos[MAXR];
    __shared__ int   s_wsum[4];
    __shared__ float s_part[4];

    if (blockIdx.x < BB) {
        // ---------------- producer: per-row run stats ----------------
        const int row = blockIdx.x;
        for (int r = t; r < MAXR; r += 256) {
            s_cnt[r] = 0.f; s_sum[r] = 0.f; s_rep[r] = 0.f; s_mse[r] = 0.f;
        }
        const float* arow = attn + row * TT;
        const float4* a4 = (const float4*)arow;
        float4 v0 = a4[t * 2], v1 = a4[t * 2 + 1];
        float a[8] = {v0.x, v0.y, v0.z, v0.w, v1.x, v1.y, v1.z, v1.w};
        float aprev = (t > 0) ? arow[t * 8 - 1] : 0.f;   // prev=false at row start

        bool pred[8], start[8];
        bool pv = aprev > CPT;
        int s = 0;
        #pragma unroll
        for (int j = 0; j < 8; j++) {
            pred[j]  = a[j] > CPT;
            start[j] = pred[j] && !pv;
            pv = pred[j];
            s += start[j] ? 1 : 0;
        }

        int v = s;
        #pragma unroll
        for (int off = 1; off < 64; off <<= 1) {
            int u = __shfl_up(v, off, 64);
            if (lane >= off) v += u;
        }
        if (lane == 63) s_wsum[wv] = v;
        __syncthreads();   // also orders LDS init before atomics

        int base = 0;
        #pragma unroll
        for (int w = 0; w < 4; w++) base += (w < wv) ? s_wsum[w] : 0;
        const int excl  = base + v - s;
        const int nruns = s_wsum[0] + s_wsum[1] + s_wsum[2] + s_wsum[3];

        int rid[8];
        int run = excl;
        #pragma unroll
        for (int j = 0; j < 8; j++) {
            if (start[j]) run++;
            rid[j] = run - 1;
            if (pred[j]) {
                atomicAdd(&s_cnt[rid[j]], 1.f);
                atomicAdd(&s_sum[rid[j]], a[j]);
                if (a[j] > CT) atomicAdd(&s_rep[rid[j]], 1.f);
                if (start[j]) s_pos[rid[j]] = t * 8 + j;
            }
        }
        __syncthreads();

        for (int r = t; r < nruns; r += 256) s_sum[r] = s_sum[r] / s_cnt[r];
        __syncthreads();

        #pragma unroll
        for (int j = 0; j < 8; j++) {
            if (pred[j]) {
                float d = a[j] - s_sum[rid[j]];
                atomicAdd(&s_mse[rid[j]], d * d);
            }
        }
        __syncthreads();

        float vid = 0.f;
        for (int r = t; r < nruns; r += 256) {
            const float c = s_cnt[r];
            vid += s_mse[r] / c;
            const float rc = s_rep[r];
            if (rc > 0.f) {
                int idx = atomicAdd(&wsI[2], 1);
                unsigned long long pk =
                      (unsigned long long)(unsigned)(row * TT + s_pos[r])
                    | ((unsigned long long)(unsigned)(int)c  << 16)
                    | ((unsigned long long)(unsigned)(int)rc << 28)
                    | (1ull << 63);
                __hip_atomic_store(&q[idx], pk, __ATOMIC_RELEASE, __HIP_MEMORY_SCOPE_AGENT);
            }
        }

        #pragma unroll
        for (int off = 32; off >= 1; off >>= 1) vid += __shfl_xor(vid, off, 64);
        if (lane == 0) s_part[wv] = vid;
        __syncthreads();
        if (t == 0) {
            atomicAdd(&wsF[0], (s_part[0] + s_part[1] + s_part[2] + s_part[3])
                                / (float)max(nruns, 1));
            __threadfence();
            atomicAdd(&wsI[4], 1);   // row published
        }
        __syncthreads();
    }

    // ---------------- consumer: work-steal qualified runs ----------------
    float fs = 0.f;
    while (true) {
        int item;
        if (lane == 0) item = atomicAdd(&wsI[5], 1);
        item = __shfl(item, 0, 64);

        unsigned long long pk = 0;
        if (lane == 0 && item < QCAP) {
            while (true) {
                pk = __hip_atomic_load(&q[item], __ATOMIC_ACQUIRE, __HIP_MEMORY_SCOPE_AGENT);
                if (pk) break;
                int done = __hip_atomic_load(&wsI[4], __ATOMIC_ACQUIRE, __HIP_MEMORY_SCOPE_AGENT);
                if (done == BB) {
                    if (item >= atomicAdd(&wsI[2], 0)) break;  // no more coming
                }
                __builtin_amdgcn_s_sleep(1);
            }
        }
        pk = (unsigned long long)__shfl((long long)pk, 0, 64);
        if (!pk) break;

        const int p0  = (int)(pk & 0xFFFFull);
        const int cnt = (int)((pk >> 16) & 0xFFFull);
        const int rep = (int)((pk >> 28) & 0xFFFull);
        const float inv_cnt = 1.f / (float)cnt;
        const float inv_rep = 1.f / (float)rep;

        float4 acc0 = {0, 0, 0, 0}, acc1 = {0, 0, 0, 0};
        for (int i = 0; i < cnt; i++) {
            const int p = p0 + i;
            const float av = attn[p];
            const float c = inv_cnt - (av > CT ? inv_rep : 0.f);
            const float4* f4 = (const float4*)(feat + (size_t)p * DD);
            float4 x = f4[lane];
            float4 y = f4[lane + 64];
            acc0.x += c * x.x; acc0.y += c * x.y; acc0.z += c * x.z; acc0.w += c * x.w;
            acc1.x += c * y.x; acc1.y += c * y.y; acc1.z += c * y.z; acc1.w += c * y.w;
        }
        fs += acc0.x * acc0.x + acc0.y * acc0.y + acc0.z * acc0.z + acc0.w * acc0.w
            + acc1.x * acc1.x + acc1.y * acc1.y + acc1.z * acc1.z + acc1.w * acc1.w;
    }

    #pragma unroll
    for (int off = 32; off >= 1; off >>= 1) fs += __shfl_xor(fs, off, 64);
    __syncthreads();              // s_part reuse barrier (producer blocks)
    if (lane == 0) s_part[wv] = fs;
    __syncthreads();

    if (t == 0) {
        float b = s_part[0] + s_part[1] + s_part[2] + s_part[3];
        if (b != 0.f) atomicAdd(&wsF[1], b);
        __threadfence();
        int ticket = atomicAdd(&wsI[3], 1);
        if (ticket == NBLK - 1) {
            int n   = atomicAdd(&wsI[2], 0);
            float fa = atomicAdd(&wsF[1], 0.f);
            float aa = atomicAdd(&wsF[0], 0.f);
            out[0] = fa / (float)DD / (float)max(n, 1) + aa / (float)BB;
        }
    }
}

extern "C" void kernel_launch(void* const* d_in, const int* in_sizes, int n_in,
                              void* d_out, int out_size, void* d_ws, size_t ws_size,
                              hipStream_t stream) {
    const float* attn = (const float*)d_in[0];
    const float* feat = (const float*)d_in[1];
    float* wsF = (float*)d_ws;
    int*   wsI = (int*)d_ws;
    unsigned long long* q = (unsigned long long*)((char*)d_ws + 256);

    hipMemsetAsync(d_ws, 0, 256 + (size_t)QCAP * 8, stream);
    k_fused<<<NBLK, 256, 0, stream>>>(attn, feat, q, wsF, wsI, (float*)d_out);
}

// Round 4
// 213.764 us; speedup vs baseline: 2.2585x; 2.2585x over previous
//
#include <hip/hip_runtime.h>

#define CT  0.7f
#define CPT 0.5f
#define BB  32
#define TT  2048
#define DD  512
#define MAXR 1025            // T/2 + 1
#define QCAP (BB * MAXR)
#define K2_BLOCKS 512
#define K2_WAVES  (K2_BLOCKS * 4)

// ws layout (header zeroed by hipMemsetAsync):
//   wsF[0] = attn-level accumulator
//   wsF[1] = feat-level accumulator
//   wsI[2] = qualified-run queue count (== n_qual)
//   wsI[3] = done-block ticket (unused now, kept for layout)
//   queue  = int4[QCAP] at byte 256: {base_pos, cnt, maskLo, maskHi}
//            mask bit i set => position base_pos+i is a rep (attn > CT)

__global__ __launch_bounds__(256) void k_attn(const float* __restrict__ attn,
                                              int4* __restrict__ queue,
                                              float* wsF, int* wsI) {
    const int row  = blockIdx.x;
    const int t    = threadIdx.x;
    const int lane = t & 63;
    const int wv   = t >> 6;

    __shared__ float s_cnt[MAXR], s_sum[MAXR], s_mse[MAXR];
    __shared__ int   s_pos[MAXR];
    __shared__ unsigned s_mskL[MAXR], s_mskH[MAXR];
    __shared__ int   s_wsum[4];
    __shared__ float s_part[4];

    for (int r = t; r < MAXR; r += 256) {
        s_cnt[r] = 0.f; s_sum[r] = 0.f; s_mse[r] = 0.f;
        s_mskL[r] = 0u; s_mskH[r] = 0u;
    }

    const float* arow = attn + row * TT;
    const float4* a4 = (const float4*)arow;
    float4 v0 = a4[t * 2], v1 = a4[t * 2 + 1];
    float a[8] = {v0.x, v0.y, v0.z, v0.w, v1.x, v1.y, v1.z, v1.w};
    float aprev = (t > 0) ? arow[t * 8 - 1] : 0.f;   // prev=false at row start

    bool pred[8], start[8];
    bool pv = aprev > CPT;
    int s = 0;
    #pragma unroll
    for (int j = 0; j < 8; j++) {
        pred[j]  = a[j] > CPT;
        start[j] = pred[j] && !pv;
        pv = pred[j];
        s += start[j] ? 1 : 0;
    }

    // wave inclusive scan (6 shfl steps) + 4-wave combine
    int v = s;
    #pragma unroll
    for (int off = 1; off < 64; off <<= 1) {
        int u = __shfl_up(v, off, 64);
        if (lane >= off) v += u;
    }
    if (lane == 63) s_wsum[wv] = v;
    __syncthreads();   // also orders LDS init before atomics

    int base = 0;
    #pragma unroll
    for (int w = 0; w < 4; w++) base += (w < wv) ? s_wsum[w] : 0;
    const int excl  = base + v - s;
    const int nruns = s_wsum[0] + s_wsum[1] + s_wsum[2] + s_wsum[3];

    int rid[8];
    int run = excl;
    #pragma unroll
    for (int j = 0; j < 8; j++) {
        if (start[j]) run++;
        rid[j] = run - 1;
        if (pred[j]) {
            atomicAdd(&s_cnt[rid[j]], 1.f);
            atomicAdd(&s_sum[rid[j]], a[j]);
            if (start[j]) s_pos[rid[j]] = t * 8 + j;
        }
    }
    __syncthreads();

    for (int r = t; r < nruns; r += 256) s_sum[r] = s_sum[r] / s_cnt[r];
    __syncthreads();

    #pragma unroll
    for (int j = 0; j < 8; j++) {
        if (pred[j]) {
            const int r = rid[j];
            float d = a[j] - s_sum[r];
            atomicAdd(&s_mse[r], d * d);
            if (a[j] > CT) {
                int off = t * 8 + j - s_pos[r];   // offset within run, < 64 for this input
                if (off < 32) atomicOr(&s_mskL[r], 1u << off);
                else if (off < 64) atomicOr(&s_mskH[r], 1u << (off - 32));
            }
        }
    }
    __syncthreads();

    float vid = 0.f;
    for (int r = t; r < nruns; r += 256) {
        const float c = s_cnt[r];
        vid += s_mse[r] / c;
        if ((s_mskL[r] | s_mskH[r]) != 0u) {
            int idx = atomicAdd(&wsI[2], 1);
            int4 dsc;
            dsc.x = row * TT + s_pos[r];
            dsc.y = (int)c;
            dsc.z = (int)s_mskL[r];
            dsc.w = (int)s_mskH[r];
            queue[idx] = dsc;
        }
    }

    #pragma unroll
    for (int off = 32; off >= 1; off >>= 1) vid += __shfl_xor(vid, off, 64);
    if (lane == 0) s_part[wv] = vid;
    __syncthreads();
    if (t == 0) {
        float tot = s_part[0] + s_part[1] + s_part[2] + s_part[3];
        atomicAdd(&wsF[0], tot / (float)max(nruns, 1));
    }
}

__global__ __launch_bounds__(256) void k_feat(const float* __restrict__ feat,
                                              const int4* __restrict__ queue,
                                              float* wsF, int* wsI,
                                              float* __restrict__ out) {
    __shared__ float s_part[4];
    const int lane = threadIdx.x & 63;
    const int wv   = threadIdx.x >> 6;
    const int wid  = blockIdx.x * 4 + wv;

    const int n = wsI[2];   // from k_attn; coherent across kernel boundary

    float s = 0.f;
    for (int item = wid; item < n; item += K2_WAVES) {
        const int4 d = queue[item];
        const unsigned long long mask =
            ((unsigned long long)(unsigned)d.w << 32) | (unsigned)d.z;
        const float inv_cnt = 1.f / (float)d.y;
        const float inv_rep = 1.f / (float)__popcll(mask);
        float4 acc0 = {0, 0, 0, 0}, acc1 = {0, 0, 0, 0};
        for (int i = 0; i < d.y; i++) {
            const float c = inv_cnt - (((mask >> i) & 1ull) ? inv_rep : 0.f);
            const float4* f4 = (const float4*)(feat + (size_t)(d.x + i) * DD);
            float4 x = f4[lane];
            float4 y = f4[lane + 64];
            acc0.x += c * x.x; acc0.y += c * x.y; acc0.z += c * x.z; acc0.w += c * x.w;
            acc1.x += c * y.x; acc1.y += c * y.y; acc1.z += c * y.z; acc1.w += c * y.w;
        }
        s += acc0.x * acc0.x + acc0.y * acc0.y + acc0.z * acc0.z + acc0.w * acc0.w
           + acc1.x * acc1.x + acc1.y * acc1.y + acc1.z * acc1.z + acc1.w * acc1.w;
    }

    #pragma unroll
    for (int off = 32; off >= 1; off >>= 1) s += __shfl_xor(s, off, 64);
    if (lane == 0) s_part[wv] = s;
    __syncthreads();

    if (threadIdx.x == 0) {
        float b = s_part[0] + s_part[1] + s_part[2] + s_part[3];
        if (b != 0.f) atomicAdd(&wsF[1], b);
        __threadfence();
        int ticket = atomicAdd(&wsI[3], 1);
        if (ticket == K2_BLOCKS - 1) {
            float fa = atomicAdd(&wsF[1], 0.f);
            float aa = atomicAdd(&wsF[0], 0.f);
            out[0] = fa / (float)DD / (float)max(n, 1) + aa / (float)BB;
        }
    }
}

extern "C" void kernel_launch(void* const* d_in, const int* in_sizes, int n_in,
                              void* d_out, int out_size, void* d_ws, size_t ws_size,
                              hipStream_t stream) {
    const float* attn = (const float*)d_in[0];
    const float* feat = (const float*)d_in[1];
    float* wsF = (float*)d_ws;
    int*   wsI = (int*)d_ws;
    int4*  queue = (int4*)((char*)d_ws + 256);

    hipMemsetAsync(d_ws, 0, 256, stream);
    k_attn<<<BB, 256, 0, stream>>>(attn, queue, wsF, wsI);
    k_feat<<<K2_BLOCKS, 256, 0, stream>>>(feat, queue, wsF, wsI, (float*)d_out);
}